// Round 7
// baseline (37.977 us; speedup 1.0000x reference)
//
#include <hip/hip_runtime.h>

typedef __attribute__((ext_vector_type(8))) short bf16x8;
typedef __attribute__((ext_vector_type(4))) float f32x4;

#define NPIX 32768

// ws byte layout:
//   [0, 32768)      W1fT bf16 [64 d][256 c]   (BN scale folded)
//   [32768, 51200)  W2T  bf16 [144 e][64 d]
//   [51200, 51456)  b1f  f32  [64]            (BN-folded bias)

__device__ __forceinline__ ushort f2bf(float f) {
    union { float f; unsigned u; } v; v.f = f;
    unsigned r = (v.u + 0x7FFFu + ((v.u >> 16) & 1u)) >> 16;  // RNE
    return (ushort)r;
}

__global__ __launch_bounds__(256) void fold_kernel(
        const float* __restrict__ W1, const float* __restrict__ b1,
        const float* __restrict__ gamma, const float* __restrict__ beta,
        const float* __restrict__ mean, const float* __restrict__ var,
        const float* __restrict__ W2, void* __restrict__ ws) {
    ushort* w1t = (ushort*)ws;
    ushort* w2t = (ushort*)ws + 16384;
    float*  b1f = (float*)((char*)ws + 51200);
    int tid = blockIdx.x * 256 + threadIdx.x;
    if (tid < 16384) {
        int d = tid >> 8, c = tid & 255;
        float scale = gamma[d] * rsqrtf(var[d] + 1e-3f);
        w1t[tid] = f2bf(W1[c * 64 + d] * scale);       // W1fT[d][c]
    }
    if (tid < 9216) {
        int e = tid >> 6, d = tid & 63;
        w2t[tid] = f2bf(W2[d * 144 + e]);              // W2T[e][d]
    }
    if (tid < 64) {
        float scale = gamma[tid] * rsqrtf(var[tid] + 1e-3f);
        b1f[tid] = (b1[tid] - mean[tid]) * scale + beta[tid];
    }
}

// Fully fused, 1 image row per block (64 px), 256 threads (4 waves),
// wave owns 16 px end-to-end. W1/W2 fragments read directly from global
// (L2-hot). XCD swizzle: 512 blocks, XCD k owns image k (4 MB = its L2).
// LDS phases (46080 B):
//   A: xs  [64][512B] @0 (32 KB, swizzled bf16 x row)
//   B: hs  [64][128B] @0 (aliases dead xs)
//   C: ks  f32 [64][148] @8192 (37888 B; overlaps dead xs rows 16..63)
__global__ __launch_bounds__(256, 2) void fused_kernel(
        const float* __restrict__ x, const void* __restrict__ ws,
        const float* __restrict__ b2, float* __restrict__ ker,
        float* __restrict__ out) {
    __shared__ __align__(16) char smem[46080];
    ushort* xs  = (ushort*)smem;                // [64 rows][512 B], swizzled
    ushort* hs  = (ushort*)smem;                // [64 rows][128 B]
    float*  ksf = (float*)(smem + 8192);        // [64][148] f32
    const int t = threadIdx.x;
    const int bid = (int)blockIdx.x;
    const int lb = (bid & 7) * 64 + (bid >> 3);  // XCD k <- image k
    const int p0 = lb * 64;
    const ushort* w1t = (const ushort*)ws;
    const ushort* w2t = (const ushort*)ws + 16384;
    const float*  b1f = (const float*)((const char*)ws + 51200);

    // ---- stage x row: f32 -> bf16, XOR-swizzled (4096 float4 chunks) ----
    const float4* xg = (const float4*)(x + (size_t)p0 * 256);
    #pragma unroll
    for (int it = 0; it < 16; it++) {
        int idx = it * 256 + t;             // 64 chunks per row
        int p = idx >> 6, c4 = idx & 63;
        float4 v = xg[idx];
        ushort4 b; b.x = f2bf(v.x); b.y = f2bf(v.y); b.z = f2bf(v.z); b.w = f2bf(v.w);
        int bcol = (c4 * 8) ^ ((p & 7) << 4);
        *(ushort4*)((char*)xs + p * 512 + bcol) = b;
    }
    __syncthreads();

    const int wv = t >> 6, ln = t & 63;
    const int r16 = ln & 15, g = ln >> 4;
    const int prow = wv * 16 + r16;

    // ---- GEMM1: 16 px x 64 d per wave; B-fragments from global ----
    f32x4 acc[4];
    #pragma unroll
    for (int dt = 0; dt < 4; dt++) {
        float bv = b1f[dt * 16 + r16];
        acc[dt] = (f32x4){bv, bv, bv, bv};
    }
    #pragma unroll
    for (int kk = 0; kk < 8; kk++) {
        int bcA = (kk * 64 + g * 16) ^ ((r16 & 7) << 4);
        bf16x8 av = *(const bf16x8*)((const char*)xs + prow * 512 + bcA);
        #pragma unroll
        for (int dt = 0; dt < 4; dt++) {
            bf16x8 bv = *(const bf16x8*)(w1t + (dt * 16 + r16) * 256 + kk * 32 + g * 8);
            acc[dt] = __builtin_amdgcn_mfma_f32_16x16x32_bf16(av, bv, acc[dt], 0, 0, 0);
        }
    }
    __syncthreads();   // xs dead; hs aliases it

    // relu -> bf16 -> hs (swizzled, wave-private rows)
    #pragma unroll
    for (int dt = 0; dt < 4; dt++) {
        #pragma unroll
        for (int r = 0; r < 4; r++) {
            int pxl = wv * 16 + g * 4 + r;            // C/D: row=(l>>4)*4+reg, col=l&15
            int bcol = ((dt * 16 + r16) * 2) ^ ((pxl & 7) << 4);
            *(ushort*)((char*)hs + pxl * 128 + bcol) = f2bf(fmaxf(acc[dt][r], 0.f));
        }
    }
    __syncthreads();

    // ---- GEMM2: 16 px x 144 e per wave; B-fragments from global ----
    f32x4 acc2[9];
    #pragma unroll
    for (int et = 0; et < 9; et++) {
        float bv = b2[et * 16 + r16];
        acc2[et] = (f32x4){bv, bv, bv, bv};
    }
    #pragma unroll
    for (int kk = 0; kk < 2; kk++) {
        int bcA = (kk * 64 + g * 16) ^ ((r16 & 7) << 4);
        bf16x8 av = *(const bf16x8*)((const char*)hs + prow * 128 + bcA);
        #pragma unroll
        for (int et = 0; et < 9; et++) {
            bf16x8 bv = *(const bf16x8*)(w2t + (et * 16 + r16) * 64 + kk * 32 + g * 8);
            acc2[et] = __builtin_amdgcn_mfma_f32_16x16x32_bf16(av, bv, acc2[et], 0, 0, 0);
        }
    }
    __syncthreads();   // hs dead; ksf region (aliasing xs rows 16..63) safe

    // ---- ker: NT store to global (output) + f32 ks in LDS ----
    #pragma unroll
    for (int et = 0; et < 9; et++) {
        #pragma unroll
        for (int r = 0; r < 4; r++) {
            int pxl = wv * 16 + g * 4 + r;
            int e = et * 16 + r16;
            float v = acc2[et][r];
            __builtin_nontemporal_store(v, &ker[(size_t)(p0 + pxl) * 144 + e]);
            ksf[pxl * 148 + e] = v;
        }
    }
    __syncthreads();

    // ---- involution: wave owns its 16 px; lane = channel chunk (4 ch) ----
    const f32x4* xv4 = (const f32x4*)x;
    const int bi = lb;            // b*64 + i
    const int i  = lb & 63;
    #pragma unroll 2
    for (int pp = 0; pp < 16; pp++) {
        const int pl = wv * 16 + pp;
        const int pix = p0 + pl;
        const int j = pix & 63;
        const float* kp = ksf + pl * 148 + (ln & 3) * 4;
        f32x4 o = {0.f, 0.f, 0.f, 0.f};
        #pragma unroll
        for (int k = 0; k < 9; k++) {
            const int di = k / 3 - 1, dj = k % 3 - 1;
            const int row = i + di, col = j + dj;
            f32x4 xv = {0.f, 0.f, 0.f, 0.f};
            if ((unsigned)row < 64u && (unsigned)col < 64u)
                xv = xv4[(size_t)((bi + di) * 64 + col) * 64 + ln];
            const f32x4 kv = *(const f32x4*)(kp + k * 16);
            o += kv * xv;
        }
        __builtin_nontemporal_store(o, &((f32x4*)out)[(size_t)pix * 64 + ln]);
    }
}

extern "C" void kernel_launch(void* const* d_in, const int* in_sizes, int n_in,
                              void* d_out, int out_size, void* d_ws, size_t ws_size,
                              hipStream_t stream) {
    const float* x     = (const float*)d_in[0];
    const float* W1    = (const float*)d_in[1];
    const float* b1    = (const float*)d_in[2];
    const float* gamma = (const float*)d_in[3];
    const float* beta  = (const float*)d_in[4];
    const float* mmean = (const float*)d_in[5];
    const float* mvar  = (const float*)d_in[6];
    const float* W2    = (const float*)d_in[7];
    const float* b2    = (const float*)d_in[8];

    float* out_main = (float*)d_out;                 // (B,H,W,C)   = 8388608 f32
    float* out_ker  = (float*)d_out + 8388608;       // (B,H,W,144) = 4718592 f32

    fold_kernel<<<64, 256, 0, stream>>>(W1, b1, gamma, beta, mmean, mvar, W2, d_ws);
    fused_kernel<<<NPIX / 64, 256, 0, stream>>>(x, d_ws, b2, out_ker, out_main);
}